// Round 7
// baseline (2004.131 us; speedup 1.0000x reference)
//
#include <hip/hip_runtime.h>
#include <math.h>

#define BB 8
#define TT 12
#define HH 128
#define WW 128
#define FF 64
#define GG 256   // 4*FF
#define PRED_LEN 6
#define TW 32    // pixels per block along W (R6: halved for 8 blocks/CU)

typedef __attribute__((ext_vector_type(8))) short short8;
typedef __attribute__((ext_vector_type(4))) float floatx4;

__device__ __forceinline__ float sigf(float x) { return 1.f / (1.f + __expf(-x)); }
__device__ __forceinline__ float tanhfast(float x) { return 1.f - 2.f / (__expf(2.f * x) + 1.f); }

__device__ __forceinline__ unsigned short f2bf(float x) {
    unsigned u = __float_as_uint(x);
    u = (u + 0x7FFFu + ((u >> 16) & 1u)) >> 16;
    return (unsigned short)u;
}

// XCD-aware bijective swizzle: 4096 blocks, 8 XCDs -> one batch per XCD,
// y-contiguous within the XCD so h halo rows are same-L2 hits.
__device__ __forceinline__ void decode_wg(int wg, int& b, int& y, int& x0) {
    int lin = (wg & 7) * 512 + (wg >> 3);   // [0,4096)
    b  = lin >> 9;                          // 512 blocks per batch
    int rem = lin & 511;
    y  = rem >> 2;
    x0 = (rem & 3) * TW;
}

// Pack B-fragments for mfma_f32_16x16x32_bf16.
// Chunks 0..17 (wr): c = tap*2+kc; lane = col + 16*kpart holds B[k][n],
//   k = kc*32 + kpart*8 + j, n = nt*16 + col.  (R1-proven.)
// Chunk 18 (x-conv + bias): B[k][n] = k<9 ? wk[k][n] : k==9 ? bias[n] : 0.
__global__ __launch_bounds__(256) void pack_wr(
    const float* __restrict__ wr, const float* __restrict__ wk,
    const float* __restrict__ bias, short8* __restrict__ packed)
{
    int e = blockIdx.x * 256 + threadIdx.x;   // 19456 entries
    if (e >= 19 * 16 * 64) return;
    int lane = e & 63;
    int rest = e >> 6;
    int nt = rest & 15;
    int ch = rest >> 4;        // 0..18
    int col = lane & 15, kpart = lane >> 4;
    int n = nt * 16 + col;
    short8 v;
    if (ch < 18) {
        int kc = ch & 1, tap = ch >> 1;
        #pragma unroll
        for (int j = 0; j < 8; ++j) {
            int k = kc * 32 + kpart * 8 + j;
            v[j] = (short)f2bf(wr[((size_t)(tap * 64 + k)) * GG + n]);
        }
    } else {
        #pragma unroll
        for (int j = 0; j < 8; ++j) {
            int k = kpart * 8 + j;
            unsigned short r = 0;
            if (k < 9) r = f2bf(wk[k * GG + n]);
            else if (k == 9) r = f2bf(bias[n]);   // bias row (A has 1.0 there)
            v[j] = (short)r;
        }
    }
    packed[e] = v;
}

// Fused ConvLSTM step: recurrent conv + input conv + bias all on MFMA,
// gates/cell update in fp32 epilogue. Block = 32 px x 256 gates; 4 waves;
// wave w owns N-tiles {w, w+4, w+8, w+12} so i,f,g,o are thread-local.
// TW=32 -> ~15.5 KB LDS, ~96 unified regs -> 8 blocks/CU (32 waves = HW max).
template<bool FIRST>
__global__ __launch_bounds__(256, 8) void lstm_step_mfma(
    const float* __restrict__ x,             // (B,T,H,W,1) fp32
    int t,
    const unsigned short* __restrict__ h_in, // (B,H,W,F) bf16
    float* __restrict__ c_buf,               // (B,H,W,F) fp32 in/out
    unsigned short* __restrict__ h_out,      // (B,H,W,F) bf16
    const short8* __restrict__ packedB)      // packed wr | wk+bias
{
    __shared__ __align__(16) unsigned short sh[3 * 34 * FF];  // swizzled bf16 h tile
    __shared__ __align__(16) unsigned short sxa[TW * 32];     // swizzled x A-fragments
    __shared__ float sx[3][34];

    const int tid = threadIdx.x;
    int b, y, x0;
    decode_wg(blockIdx.x, b, y, x0);
    char* shb = (char*)sh;

    if (!FIRST) {
        // stage h tile: 3 rows x 34 cols x 64 ch bf16, 16B chunks, XOR-swizzled
        for (int i = tid; i < 3 * 34 * 8; i += 256) {
            int cq  = i & 7;
            int rc  = i >> 3;
            int col = rc % 34, r = rc / 34;
            int gy = y + r - 1, gx = x0 + col - 1;
            uint4 v = make_uint4(0u, 0u, 0u, 0u);
            if ((unsigned)gy < HH && (unsigned)gx < WW)
                v = *(const uint4*)(h_in + ((((size_t)b * HH + gy) * WW + gx) * FF + cq * 8));
            int byte = ((r * 34 + col) * FF + cq * 8) * 2;
            byte ^= ((col & 7) << 4);
            *(uint4*)(shb + byte) = v;
        }
    }
    // stage x tile (fp32)
    for (int i = tid; i < 3 * 34; i += 256) {
        int col = i % 34, r = i / 34;
        int gy = y + r - 1, gx = x0 + col - 1;
        float v = 0.f;
        if ((unsigned)gy < HH && (unsigned)gx < WW)
            v = x[(((size_t)b * TT + t) * HH + gy) * WW + gx];
        sx[r][col] = v;
    }
    __syncthreads();

    // build x A-fragment tile: sxa[px][k] = k<9 ? tap k : k==9 ? 1.0 : 0
    if (tid < TW * 4) {
        int px = tid >> 2, kpc = tid & 3;
        short8 v;
        #pragma unroll
        for (int j = 0; j < 8; ++j) {
            int k = kpc * 8 + j;
            unsigned short r = 0;
            if (k < 9) r = f2bf(sx[k / 3][px + (k % 3)]);
            else if (k == 9) r = (unsigned short)0x3F80;   // 1.0 multiplies bias row
            v[j] = (short)r;
        }
        int byte = (px * 64 + kpc * 16) ^ ((px & 7) << 4);
        *(short8*)((char*)sxa + byte) = v;
    }
    __syncthreads();

    const int l  = tid & 63;
    const int w  = tid >> 6;
    const int lc = l & 15;
    const int kp = l >> 4;
    const int gcol = w * 16 + lc;   // feature index 0..63
    const size_t base = (((size_t)b * HH + y) * WW + x0) * FF + gcol;

    // hoist the c-state loads: independent of acc, latency hides under MFMA
    float cp[2][4];
    if (!FIRST) {
        #pragma unroll
        for (int m = 0; m < 2; ++m)
            #pragma unroll
            for (int r = 0; r < 4; ++r)
                cp[m][r] = c_buf[base + (size_t)(m * 16 + kp * 4 + r) * FF];
    }

    floatx4 acc[2][4];
    #pragma unroll
    for (int m = 0; m < 2; ++m)
        #pragma unroll
        for (int q = 0; q < 4; ++q)
            acc[m][q] = (floatx4){0.f, 0.f, 0.f, 0.f};

    // merged chunk loop: 0..17 = recurrent conv, 18 = input conv + bias
    #pragma unroll
    for (int c = FIRST ? 18 : 0; c < 19; ++c) {
        short8 af[2], bf[4];
        if (c < 18) {
            const int tap_ = c >> 1, kc_ = c & 1, dy_ = tap_ / 3, dx_ = tap_ % 3;
            #pragma unroll
            for (int m_ = 0; m_ < 2; ++m_) {
                const int col_ = m_ * 16 + lc + dx_;
                int byte_ = ((dy_ * 34 + col_) * FF + kc_ * 32 + kp * 8) * 2;
                byte_ ^= ((col_ & 7) << 4);
                af[m_] = *(const short8*)(shb + byte_);
            }
        } else {
            #pragma unroll
            for (int m_ = 0; m_ < 2; ++m_) {
                const int px_ = m_ * 16 + lc;
                int byte_ = (px_ * 64 + kp * 16) ^ ((px_ & 7) << 4);
                af[m_] = *(const short8*)((const char*)sxa + byte_);
            }
        }
        #pragma unroll
        for (int q_ = 0; q_ < 4; ++q_)
            bf[q_] = packedB[(size_t)(c * 16 + (q_ * 4 + w)) * 64 + l];
        #pragma unroll
        for (int m_ = 0; m_ < 2; ++m_)
            #pragma unroll
            for (int q_ = 0; q_ < 4; ++q_)
                acc[m_][q_] = __builtin_amdgcn_mfma_f32_16x16x32_bf16(
                    af[m_], bf[q_], acc[m_][q_], 0, 0, 0);
    }

    // epilogue: gates + cell update only (Keras order i,f,g,o)
    #pragma unroll
    for (int m = 0; m < 2; ++m) {
        #pragma unroll
        for (int r = 0; r < 4; ++r) {
            int p = m * 16 + kp * 4 + r;   // pixel within tile
            size_t idx = base + (size_t)p * FF;
            float cpv = FIRST ? 0.f : cp[m][r];
            float iv = sigf(acc[m][0][r]);
            float fv = sigf(acc[m][1][r]);
            float gv = tanhfast(acc[m][2][r]);
            float ov = sigf(acc[m][3][r]);
            float cn = fv * cpv + iv * gv;
            float hn = ov * tanhfast(cn);
            c_buf[idx] = cn;
            h_out[idx] = f2bf(hn);
        }
    }
}

// Fused decoder iteration (XCD-swizzled 1D grid, same decode):
//   pred = sigmoid(conv3x3(cur_in, w_out) + b_out)  -> out[:, ti]
//   cur_out = relu(pred * w_proj + b_proj)          (bf16)
__global__ __launch_bounds__(256) void dec_fused(
    const unsigned short* __restrict__ cur_in, const float* __restrict__ w_out,
    const float* __restrict__ b_out, const float* __restrict__ w_proj,
    const float* __restrict__ b_proj, float* __restrict__ out,
    unsigned short* __restrict__ cur_out, int ti)
{
    int tid = threadIdx.x;
    int j  = tid & 7;
    int pp = tid >> 3;
    int b, y, x0;
    decode_wg(blockIdx.x, b, y, x0);
    int xx = x0 + pp;

    float s = 0.f;
    for (int dy = 0; dy < 3; ++dy) {
        int gy = y + dy - 1;
        if ((unsigned)gy >= HH) continue;
        #pragma unroll
        for (int dx = 0; dx < 3; ++dx) {
            int gx = xx + dx - 1;
            if ((unsigned)gx >= WW) continue;
            const uint4 cv = *(const uint4*)(cur_in + ((((size_t)b * HH + gy) * WW + gx) * FF + j * 8));
            const float4* wp = (const float4*)&w_out[(dy * 3 + dx) * FF + j * 8];
            float4 w0 = wp[0], w1 = wp[1];
            unsigned cx = cv.x, cy = cv.y, cz = cv.z, cw = cv.w;
            s += __uint_as_float(cx << 16) * w0.x + __uint_as_float(cx & 0xFFFF0000u) * w0.y
               + __uint_as_float(cy << 16) * w0.z + __uint_as_float(cy & 0xFFFF0000u) * w0.w
               + __uint_as_float(cz << 16) * w1.x + __uint_as_float(cz & 0xFFFF0000u) * w1.y
               + __uint_as_float(cw << 16) * w1.z + __uint_as_float(cw & 0xFFFF0000u) * w1.w;
        }
    }
    s += __shfl_xor(s, 1);
    s += __shfl_xor(s, 2);
    s += __shfl_xor(s, 4);
    float pv = sigf(s + b_out[0]);

    size_t pix = (((size_t)b * HH + y) * WW + xx);
    if (j == 0)
        out[((size_t)b * PRED_LEN + ti) * (HH * WW) + (size_t)y * WW + xx] = pv;

    const float4* wp = (const float4*)w_proj;
    const float4* bp = (const float4*)b_proj;
    float4 w0 = wp[j * 2], w1 = wp[j * 2 + 1];
    float4 b0 = bp[j * 2], b1 = bp[j * 2 + 1];
    short8 o;
    o[0] = (short)f2bf(fmaxf(fmaf(pv, w0.x, b0.x), 0.f));
    o[1] = (short)f2bf(fmaxf(fmaf(pv, w0.y, b0.y), 0.f));
    o[2] = (short)f2bf(fmaxf(fmaf(pv, w0.z, b0.z), 0.f));
    o[3] = (short)f2bf(fmaxf(fmaf(pv, w0.w, b0.w), 0.f));
    o[4] = (short)f2bf(fmaxf(fmaf(pv, w1.x, b1.x), 0.f));
    o[5] = (short)f2bf(fmaxf(fmaf(pv, w1.y, b1.y), 0.f));
    o[6] = (short)f2bf(fmaxf(fmaf(pv, w1.z, b1.z), 0.f));
    o[7] = (short)f2bf(fmaxf(fmaf(pv, w1.w, b1.w), 0.f));
    *(short8*)(cur_out + pix * FF + j * 8) = o;
}

extern "C" void kernel_launch(void* const* d_in, const int* in_sizes, int n_in,
                              void* d_out, int out_size, void* d_ws, size_t ws_size,
                              hipStream_t stream)
{
    const float* x      = (const float*)d_in[0];
    const float* wk     = (const float*)d_in[1];
    const float* wr     = (const float*)d_in[2];
    const float* bias   = (const float*)d_in[3];
    const float* w_out  = (const float*)d_in[4];
    const float* b_out  = (const float*)d_in[5];
    const float* w_proj = (const float*)d_in[6];
    const float* b_proj = (const float*)d_in[7];
    float* out = (float*)d_out;

    const size_t SB = (size_t)BB * HH * WW * FF;   // 8388608 elems
    unsigned short* h_a = (unsigned short*)d_ws;
    unsigned short* h_b = h_a + SB;
    float* cb = (float*)((char*)d_ws + 2 * SB * sizeof(unsigned short));
    short8* packed = (short8*)((char*)cb + SB * sizeof(float));  // 19456*16 B

    pack_wr<<<76, 256, 0, stream>>>(wr, wk, bias, packed);

    const int NBLK = (WW / TW) * HH * BB;   // 4096
    unsigned short* bufs[2] = {h_a, h_b};
    // FIRST writes every c/h element before any read -> no memset needed.
    lstm_step_mfma<true><<<NBLK, 256, 0, stream>>>(x, 0, bufs[0], cb, bufs[1], packed);
    for (int t = 1; t < TT; ++t) {
        lstm_step_mfma<false><<<NBLK, 256, 0, stream>>>(x, t, bufs[t & 1], cb,
                                                        bufs[(t + 1) & 1], packed);
    }

    for (int ti = 0; ti < PRED_LEN; ++ti) {
        dec_fused<<<NBLK, 256, 0, stream>>>(
            bufs[ti & 1], w_out, b_out, w_proj, b_proj, out, bufs[(ti + 1) & 1], ti);
    }
}

// Round 8
// 1111.746 us; speedup vs baseline: 1.8027x; 1.8027x over previous
//
#include <hip/hip_runtime.h>
#include <math.h>

#define BB 8
#define TT 12
#define HH 128
#define WW 128
#define FF 64
#define GG 256   // 4*FF
#define PRED_LEN 6
#define TW 32    // pixels per block along W

typedef __attribute__((ext_vector_type(8))) short short8;
typedef __attribute__((ext_vector_type(4))) float floatx4;

__device__ __forceinline__ float sigf(float x) { return 1.f / (1.f + __expf(-x)); }
__device__ __forceinline__ float tanhfast(float x) { return 1.f - 2.f / (__expf(2.f * x) + 1.f); }

__device__ __forceinline__ unsigned short f2bf(float x) {
    unsigned u = __float_as_uint(x);
    u = (u + 0x7FFFu + ((u >> 16) & 1u)) >> 16;
    return (unsigned short)u;
}

// Step-kernel swizzle: 8192 blocks -> batch b == XCD (8192%8==0, bijective).
// rem: y (7b) | x-tile (2b) | gate-half (1b), y-major for halo L2 locality.
__device__ __forceinline__ void decode_step(int wg, int& b, int& y, int& x0, int& half) {
    int lin = (wg & 7) * 1024 + (wg >> 3);
    b = lin >> 10;
    int rem = lin & 1023;
    y = rem >> 3;
    x0 = ((rem >> 1) & 3) * TW;
    half = rem & 1;
}

// Decoder swizzle (R6-proven): 4096 blocks.
__device__ __forceinline__ void decode_dec(int wg, int& b, int& y, int& x0) {
    int lin = (wg & 7) * 512 + (wg >> 3);
    b = lin >> 9;
    int rem = lin & 511;
    y = rem >> 2;
    x0 = (rem & 3) * TW;
}

// Pack B-fragments for mfma_f32_16x16x32_bf16.  (R5-proven, unchanged.)
// Chunks 0..17 (wr): c = tap*2+kc; lane = col + 16*kpart holds B[k][n],
//   k = kc*32 + kpart*8 + j, n = nt*16 + col.
// Chunk 18 (x-conv + bias): B[k][n] = k<9 ? wk[k][n] : k==9 ? bias[n] : 0.
__global__ __launch_bounds__(256) void pack_wr(
    const float* __restrict__ wr, const float* __restrict__ wk,
    const float* __restrict__ bias, short8* __restrict__ packed)
{
    int e = blockIdx.x * 256 + threadIdx.x;   // 19456 entries
    if (e >= 19 * 16 * 64) return;
    int lane = e & 63;
    int rest = e >> 6;
    int nt = rest & 15;
    int ch = rest >> 4;        // 0..18
    int col = lane & 15, kpart = lane >> 4;
    int n = nt * 16 + col;
    short8 v;
    if (ch < 18) {
        int kc = ch & 1, tap = ch >> 1;
        #pragma unroll
        for (int j = 0; j < 8; ++j) {
            int k = kc * 32 + kpart * 8 + j;
            v[j] = (short)f2bf(wr[((size_t)(tap * 64 + k)) * GG + n]);
        }
    } else {
        #pragma unroll
        for (int j = 0; j < 8; ++j) {
            int k = kpart * 8 + j;
            unsigned short r = 0;
            if (k < 9) r = f2bf(wk[k * GG + n]);
            else if (k == 9) r = f2bf(bias[n]);   // bias row (A has 1.0 there)
            v[j] = (short)r;
        }
    }
    packed[e] = v;
}

// Fused ConvLSTM step. Block = 32 px x 128 gate-cols (one feature-half, all
// 4 gates: N-tiles {g*4 + half*2 + j}), 4 waves; wave w: m = w>>1 (M-tile),
// j = w&1 (feature sub-group). Per-wave regs: acc 16 + af 8 + bf 16 + addr
// ~58 <= 64 -> true 8 waves/SIMD without spill (R6 spilled at core=64).
template<bool FIRST>
__global__ __launch_bounds__(256, 8) void lstm_step_mfma(
    const float* __restrict__ x,             // (B,T,H,W,1) fp32
    int t,
    const unsigned short* __restrict__ h_in, // (B,H,W,F) bf16
    float* __restrict__ c_buf,               // (B,H,W,F) fp32 in/out
    unsigned short* __restrict__ h_out,      // (B,H,W,F) bf16
    const short8* __restrict__ packedB)      // packed wr | wk+bias
{
    __shared__ __align__(16) unsigned short sh[3 * 34 * FF];  // swizzled bf16 h tile
    __shared__ __align__(16) unsigned short sxa[TW * 32];     // swizzled x A-fragments
    __shared__ float sx[3][34];

    const int tid = threadIdx.x;
    int b, y, x0, half;
    decode_step(blockIdx.x, b, y, x0, half);
    char* shb = (char*)sh;

    if (!FIRST) {
        // stage h tile: 3 rows x 34 cols x 64 ch bf16, 16B chunks, XOR-swizzled
        for (int i = tid; i < 3 * 34 * 8; i += 256) {
            int cq  = i & 7;
            int rc  = i >> 3;
            int col = rc % 34, r = rc / 34;
            int gy = y + r - 1, gx = x0 + col - 1;
            uint4 v = make_uint4(0u, 0u, 0u, 0u);
            if ((unsigned)gy < HH && (unsigned)gx < WW)
                v = *(const uint4*)(h_in + ((((size_t)b * HH + gy) * WW + gx) * FF + cq * 8));
            int byte = ((r * 34 + col) * FF + cq * 8) * 2;
            byte ^= ((col & 7) << 4);
            *(uint4*)(shb + byte) = v;
        }
    }
    // stage x tile (fp32)
    for (int i = tid; i < 3 * 34; i += 256) {
        int col = i % 34, r = i / 34;
        int gy = y + r - 1, gx = x0 + col - 1;
        float v = 0.f;
        if ((unsigned)gy < HH && (unsigned)gx < WW)
            v = x[(((size_t)b * TT + t) * HH + gy) * WW + gx];
        sx[r][col] = v;
    }
    __syncthreads();

    // build x A-fragment tile: sxa[px][k] = k<9 ? tap k : k==9 ? 1.0 : 0
    if (tid < TW * 4) {
        int px = tid >> 2, kpc = tid & 3;
        short8 v;
        #pragma unroll
        for (int j = 0; j < 8; ++j) {
            int k = kpc * 8 + j;
            unsigned short r = 0;
            if (k < 9) r = f2bf(sx[k / 3][px + (k % 3)]);
            else if (k == 9) r = (unsigned short)0x3F80;   // 1.0 multiplies bias row
            v[j] = (short)r;
        }
        int byte = (px * 64 + kpc * 16) ^ ((px & 7) << 4);
        *(short8*)((char*)sxa + byte) = v;
    }
    __syncthreads();

    const int l  = tid & 63;
    const int w  = tid >> 6;
    const int lc = l & 15;
    const int kp = l >> 4;
    const int j  = w & 1;      // feature sub-group
    const int m  = w >> 1;     // M-tile (16-px group)
    const int gcol = half * 32 + j * 16 + lc;   // feature index 0..63
    const size_t base = (((size_t)b * HH + y) * WW + x0) * FF + gcol;

    // hoist c-state loads: independent of acc, latency hides under MFMA
    float cp[4];
    if (!FIRST) {
        #pragma unroll
        for (int r = 0; r < 4; ++r)
            cp[r] = c_buf[base + (size_t)(m * 16 + kp * 4 + r) * FF];
    }

    floatx4 acc[4];   // one per gate g: N-tile g*4 + half*2 + j
    #pragma unroll
    for (int g = 0; g < 4; ++g)
        acc[g] = (floatx4){0.f, 0.f, 0.f, 0.f};

    // merged chunk loop: 0..17 = recurrent conv, 18 = input conv + bias
    #pragma unroll
    for (int c = FIRST ? 18 : 0; c < 19; ++c) {
        short8 af, bf[4];
        if (c < 18) {
            const int tap_ = c >> 1, kc_ = c & 1, dy_ = tap_ / 3, dx_ = tap_ % 3;
            const int col_ = m * 16 + lc + dx_;
            int byte_ = ((dy_ * 34 + col_) * FF + kc_ * 32 + kp * 8) * 2;
            byte_ ^= ((col_ & 7) << 4);
            af = *(const short8*)(shb + byte_);
        } else {
            const int px_ = m * 16 + lc;
            int byte_ = (px_ * 64 + kp * 16) ^ ((px_ & 7) << 4);
            af = *(const short8*)((const char*)sxa + byte_);
        }
        #pragma unroll
        for (int g = 0; g < 4; ++g)
            bf[g] = packedB[(size_t)(c * 16 + (g * 4 + half * 2 + j)) * 64 + l];
        #pragma unroll
        for (int g = 0; g < 4; ++g)
            acc[g] = __builtin_amdgcn_mfma_f32_16x16x32_bf16(af, bf[g], acc[g], 0, 0, 0);
    }

    // epilogue: gates + cell update (Keras order i,f,g,o)
    #pragma unroll
    for (int r = 0; r < 4; ++r) {
        int p = m * 16 + kp * 4 + r;   // pixel within tile
        size_t idx = base + (size_t)p * FF;
        float cpv = FIRST ? 0.f : cp[r];
        float iv = sigf(acc[0][r]);
        float fv = sigf(acc[1][r]);
        float gv = tanhfast(acc[2][r]);
        float ov = sigf(acc[3][r]);
        float cn = fv * cpv + iv * gv;
        float hn = ov * tanhfast(cn);
        c_buf[idx] = cn;
        h_out[idx] = f2bf(hn);
    }
}

// Fused decoder iteration (R6-proven):
//   pred = sigmoid(conv3x3(cur_in, w_out) + b_out)  -> out[:, ti]
//   cur_out = relu(pred * w_proj + b_proj)          (bf16)
__global__ __launch_bounds__(256) void dec_fused(
    const unsigned short* __restrict__ cur_in, const float* __restrict__ w_out,
    const float* __restrict__ b_out, const float* __restrict__ w_proj,
    const float* __restrict__ b_proj, float* __restrict__ out,
    unsigned short* __restrict__ cur_out, int ti)
{
    int tid = threadIdx.x;
    int j  = tid & 7;
    int pp = tid >> 3;
    int b, y, x0;
    decode_dec(blockIdx.x, b, y, x0);
    int xx = x0 + pp;

    float s = 0.f;
    for (int dy = 0; dy < 3; ++dy) {
        int gy = y + dy - 1;
        if ((unsigned)gy >= HH) continue;
        #pragma unroll
        for (int dx = 0; dx < 3; ++dx) {
            int gx = xx + dx - 1;
            if ((unsigned)gx >= WW) continue;
            const uint4 cv = *(const uint4*)(cur_in + ((((size_t)b * HH + gy) * WW + gx) * FF + j * 8));
            const float4* wp = (const float4*)&w_out[(dy * 3 + dx) * FF + j * 8];
            float4 w0 = wp[0], w1 = wp[1];
            unsigned cx = cv.x, cy = cv.y, cz = cv.z, cw = cv.w;
            s += __uint_as_float(cx << 16) * w0.x + __uint_as_float(cx & 0xFFFF0000u) * w0.y
               + __uint_as_float(cy << 16) * w0.z + __uint_as_float(cy & 0xFFFF0000u) * w0.w
               + __uint_as_float(cz << 16) * w1.x + __uint_as_float(cz & 0xFFFF0000u) * w1.y
               + __uint_as_float(cw << 16) * w1.z + __uint_as_float(cw & 0xFFFF0000u) * w1.w;
        }
    }
    s += __shfl_xor(s, 1);
    s += __shfl_xor(s, 2);
    s += __shfl_xor(s, 4);
    float pv = sigf(s + b_out[0]);

    size_t pix = (((size_t)b * HH + y) * WW + xx);
    if (j == 0)
        out[((size_t)b * PRED_LEN + ti) * (HH * WW) + (size_t)y * WW + xx] = pv;

    const float4* wp = (const float4*)w_proj;
    const float4* bp = (const float4*)b_proj;
    float4 w0 = wp[j * 2], w1 = wp[j * 2 + 1];
    float4 b0 = bp[j * 2], b1 = bp[j * 2 + 1];
    short8 o;
    o[0] = (short)f2bf(fmaxf(fmaf(pv, w0.x, b0.x), 0.f));
    o[1] = (short)f2bf(fmaxf(fmaf(pv, w0.y, b0.y), 0.f));
    o[2] = (short)f2bf(fmaxf(fmaf(pv, w0.z, b0.z), 0.f));
    o[3] = (short)f2bf(fmaxf(fmaf(pv, w0.w, b0.w), 0.f));
    o[4] = (short)f2bf(fmaxf(fmaf(pv, w1.x, b1.x), 0.f));
    o[5] = (short)f2bf(fmaxf(fmaf(pv, w1.y, b1.y), 0.f));
    o[6] = (short)f2bf(fmaxf(fmaf(pv, w1.z, b1.z), 0.f));
    o[7] = (short)f2bf(fmaxf(fmaf(pv, w1.w, b1.w), 0.f));
    *(short8*)(cur_out + pix * FF + j * 8) = o;
}

extern "C" void kernel_launch(void* const* d_in, const int* in_sizes, int n_in,
                              void* d_out, int out_size, void* d_ws, size_t ws_size,
                              hipStream_t stream)
{
    const float* x      = (const float*)d_in[0];
    const float* wk     = (const float*)d_in[1];
    const float* wr     = (const float*)d_in[2];
    const float* bias   = (const float*)d_in[3];
    const float* w_out  = (const float*)d_in[4];
    const float* b_out  = (const float*)d_in[5];
    const float* w_proj = (const float*)d_in[6];
    const float* b_proj = (const float*)d_in[7];
    float* out = (float*)d_out;

    const size_t SB = (size_t)BB * HH * WW * FF;   // 8388608 elems
    unsigned short* h_a = (unsigned short*)d_ws;
    unsigned short* h_b = h_a + SB;
    float* cb = (float*)((char*)d_ws + 2 * SB * sizeof(unsigned short));
    short8* packed = (short8*)((char*)cb + SB * sizeof(float));  // 19456*16 B

    pack_wr<<<76, 256, 0, stream>>>(wr, wk, bias, packed);

    const int NBLK_STEP = (WW / TW) * HH * BB * 2;   // 8192 (x2 gate-halves)
    const int NBLK_DEC  = (WW / TW) * HH * BB;       // 4096
    unsigned short* bufs[2] = {h_a, h_b};
    // FIRST writes every c/h element before any read -> no memset needed.
    lstm_step_mfma<true><<<NBLK_STEP, 256, 0, stream>>>(x, 0, bufs[0], cb, bufs[1], packed);
    for (int t = 1; t < TT; ++t) {
        lstm_step_mfma<false><<<NBLK_STEP, 256, 0, stream>>>(x, t, bufs[t & 1], cb,
                                                             bufs[(t + 1) & 1], packed);
    }

    for (int ti = 0; ti < PRED_LEN; ++ti) {
        dec_fused<<<NBLK_DEC, 256, 0, stream>>>(
            bufs[ti & 1], w_out, b_out, w_proj, b_proj, out, bufs[(ti + 1) & 1], ti);
    }
}

// Round 9
// 818.848 us; speedup vs baseline: 2.4475x; 1.3577x over previous
//
#include <hip/hip_runtime.h>
#include <math.h>

#define BB 8
#define TT 12
#define HH 128
#define WW 128
#define FF 64
#define GG 256   // 4*FF
#define PRED_LEN 6
#define TW 64     // pixels per block along W (step kernel)
#define TWD 32    // pixels per block along W (decoder)

typedef __attribute__((ext_vector_type(8))) short short8;
typedef __attribute__((ext_vector_type(4))) float floatx4;

__device__ __forceinline__ float sigf(float x) { return 1.f / (1.f + __expf(-x)); }
__device__ __forceinline__ float tanhfast(float x) { return 1.f - 2.f / (__expf(2.f * x) + 1.f); }

__device__ __forceinline__ unsigned short f2bf(float x) {
    unsigned u = __float_as_uint(x);
    u = (u + 0x7FFFu + ((u >> 16) & 1u)) >> 16;
    return (unsigned short)u;
}

// Step-grid XCD swizzle: 2048 blocks, 2048%8==0 -> bijective.
// One batch per XCD (256 blocks), y-contiguous: h halo rows produced and
// consumed on the same XCD's L2 (R7 evidence: FETCH 58->28 MB).
__device__ __forceinline__ void decode_step(int wg, int& b, int& y, int& x0) {
    int lin = (wg & 7) * 256 + (wg >> 3);   // [0,2048)
    b = lin >> 8;                           // 256 blocks per batch
    int rem = lin & 255;
    y = rem >> 1;
    x0 = (rem & 1) * TW;
}

// Decoder swizzle (R6/R7-proven): 4096 blocks.
__device__ __forceinline__ void decode_dec(int wg, int& b, int& y, int& x0) {
    int lin = (wg & 7) * 512 + (wg >> 3);
    b = lin >> 9;
    int rem = lin & 511;
    y = rem >> 2;
    x0 = (rem & 3) * TWD;
}

// Pack B-fragments for mfma_f32_16x16x32_bf16.  (R5-proven, unchanged.)
// Chunks 0..17 (wr): c = tap*2+kc; lane = col + 16*kpart holds B[k][n],
//   k = kc*32 + kpart*8 + j, n = nt*16 + col.
// Chunk 18 (x-conv + bias): B[k][n] = k<9 ? wk[k][n] : k==9 ? bias[n] : 0.
__global__ __launch_bounds__(256) void pack_wr(
    const float* __restrict__ wr, const float* __restrict__ wk,
    const float* __restrict__ bias, short8* __restrict__ packed)
{
    int e = blockIdx.x * 256 + threadIdx.x;   // 19456 entries
    if (e >= 19 * 16 * 64) return;
    int lane = e & 63;
    int rest = e >> 6;
    int nt = rest & 15;
    int ch = rest >> 4;        // 0..18
    int col = lane & 15, kpart = lane >> 4;
    int n = nt * 16 + col;
    short8 v;
    if (ch < 18) {
        int kc = ch & 1, tap = ch >> 1;
        #pragma unroll
        for (int j = 0; j < 8; ++j) {
            int k = kc * 32 + kpart * 8 + j;
            v[j] = (short)f2bf(wr[((size_t)(tap * 64 + k)) * GG + n]);
        }
    } else {
        #pragma unroll
        for (int j = 0; j < 8; ++j) {
            int k = kpart * 8 + j;
            unsigned short r = 0;
            if (k < 9) r = f2bf(wk[k * GG + n]);
            else if (k == 9) r = f2bf(bias[n]);   // bias row (A has 1.0 there)
            v[j] = (short)r;
        }
    }
    packed[e] = v;
}

// Fused ConvLSTM step (R5-proven structure + XCD swizzle).
// Block = 64 px x 256 gates; 4 waves; wave w owns N-tiles {w, w+4, w+8, w+12}
// so i,f,g,o per feature are thread-local. __launch_bounds__(256,4): keep
// unified VGPR+AGPR <=128 (R4-proven; R6's (256,8) spilled).
template<bool FIRST>
__global__ __launch_bounds__(256, 4) void lstm_step_mfma(
    const float* __restrict__ x,             // (B,T,H,W,1) fp32
    int t,
    const unsigned short* __restrict__ h_in, // (B,H,W,F) bf16
    float* __restrict__ c_buf,               // (B,H,W,F) fp32 in/out
    unsigned short* __restrict__ h_out,      // (B,H,W,F) bf16
    const short8* __restrict__ packedB)      // packed wr | wk+bias
{
    __shared__ __align__(16) unsigned short sh[3 * 66 * FF];  // swizzled bf16 h tile
    __shared__ __align__(16) unsigned short sxa[TW * 32];     // swizzled x A-fragments
    __shared__ float sx[3][66];

    const int tid = threadIdx.x;
    int b, y, x0;
    decode_step(blockIdx.x, b, y, x0);
    char* shb = (char*)sh;

    if (!FIRST) {
        // stage h tile: 3 rows x 66 cols x 64 ch bf16, 16B chunks, XOR-swizzled
        for (int i = tid; i < 3 * 66 * 8; i += 256) {
            int cq  = i & 7;
            int rc  = i >> 3;
            int col = rc % 66, r = rc / 66;
            int gy = y + r - 1, gx = x0 + col - 1;
            uint4 v = make_uint4(0u, 0u, 0u, 0u);
            if ((unsigned)gy < HH && (unsigned)gx < WW)
                v = *(const uint4*)(h_in + ((((size_t)b * HH + gy) * WW + gx) * FF + cq * 8));
            int byte = ((r * 66 + col) * FF + cq * 8) * 2;
            byte ^= ((col & 7) << 4);
            *(uint4*)(shb + byte) = v;
        }
    }
    // stage x tile (fp32)
    for (int i = tid; i < 3 * 66; i += 256) {
        int col = i % 66, r = i / 66;
        int gy = y + r - 1, gx = x0 + col - 1;
        float v = 0.f;
        if ((unsigned)gy < HH && (unsigned)gx < WW)
            v = x[(((size_t)b * TT + t) * HH + gy) * WW + gx];
        sx[r][col] = v;
    }
    __syncthreads();

    // build x A-fragment tile: sxa[px][k] = k<9 ? tap k : k==9 ? 1.0 : 0
    {
        int px = tid >> 2, kpc = tid & 3;
        short8 v;
        #pragma unroll
        for (int j = 0; j < 8; ++j) {
            int k = kpc * 8 + j;
            unsigned short r = 0;
            if (k < 9) r = f2bf(sx[k / 3][px + (k % 3)]);
            else if (k == 9) r = (unsigned short)0x3F80;   // 1.0 multiplies bias row
            v[j] = (short)r;
        }
        int byte = (px * 64 + kpc * 16) ^ ((px & 7) << 4);
        *(short8*)((char*)sxa + byte) = v;
    }
    __syncthreads();

    const int l  = tid & 63;
    const int w  = tid >> 6;
    const int lc = l & 15;
    const int kp = l >> 4;
    const int gcol = w * 16 + lc;   // feature index 0..63

    floatx4 acc[4][4];
    #pragma unroll
    for (int m = 0; m < 4; ++m)
        #pragma unroll
        for (int q = 0; q < 4; ++q)
            acc[m][q] = (floatx4){0.f, 0.f, 0.f, 0.f};

    if (!FIRST) {
        // recurrent conv: 18 chunks, single-buffered (R4/R5-proven)
        #pragma unroll
        for (int c = 0; c < 18; ++c) {
            const int tap_ = c >> 1, kc_ = c & 1, dy_ = tap_ / 3, dx_ = tap_ % 3;
            short8 af[4], bf[4];
            #pragma unroll
            for (int m_ = 0; m_ < 4; ++m_) {
                const int col_ = m_ * 16 + lc + dx_;
                int byte_ = ((dy_ * 66 + col_) * FF + kc_ * 32 + kp * 8) * 2;
                byte_ ^= ((col_ & 7) << 4);
                af[m_] = *(const short8*)(shb + byte_);
            }
            #pragma unroll
            for (int q_ = 0; q_ < 4; ++q_)
                bf[q_] = packedB[(size_t)(c * 16 + (q_ * 4 + w)) * 64 + l];
            #pragma unroll
            for (int m_ = 0; m_ < 4; ++m_)
                #pragma unroll
                for (int q_ = 0; q_ < 4; ++q_)
                    acc[m_][q_] = __builtin_amdgcn_mfma_f32_16x16x32_bf16(
                        af[m_], bf[q_], acc[m_][q_], 0, 0, 0);
        }
    }
    {
        // chunk 18: input conv + bias
        short8 af[4], bf[4];
        #pragma unroll
        for (int m_ = 0; m_ < 4; ++m_) {
            const int px_ = m_ * 16 + lc;
            int byte_ = (px_ * 64 + kp * 16) ^ ((px_ & 7) << 4);
            af[m_] = *(const short8*)((const char*)sxa + byte_);
        }
        #pragma unroll
        for (int q_ = 0; q_ < 4; ++q_)
            bf[q_] = packedB[(size_t)(18 * 16 + (q_ * 4 + w)) * 64 + l];
        #pragma unroll
        for (int m_ = 0; m_ < 4; ++m_)
            #pragma unroll
            for (int q_ = 0; q_ < 4; ++q_)
                acc[m_][q_] = __builtin_amdgcn_mfma_f32_16x16x32_bf16(
                    af[m_], bf[q_], acc[m_][q_], 0, 0, 0);
    }

    // epilogue: gates + cell update only (Keras order i,f,g,o)
    #pragma unroll
    for (int m = 0; m < 4; ++m) {
        #pragma unroll
        for (int r = 0; r < 4; ++r) {
            int p = m * 16 + kp * 4 + r;   // pixel within tile
            size_t idx = (((size_t)b * HH + y) * WW + (x0 + p)) * FF + gcol;
            float cp = FIRST ? 0.f : c_buf[idx];
            float iv = sigf(acc[m][0][r]);
            float fv = sigf(acc[m][1][r]);
            float gv = tanhfast(acc[m][2][r]);
            float ov = sigf(acc[m][3][r]);
            float cn = fv * cp + iv * gv;
            float hn = ov * tanhfast(cn);
            c_buf[idx] = cn;
            h_out[idx] = f2bf(hn);
        }
    }
}

// Fused decoder iteration (R6/R7-proven):
//   pred = sigmoid(conv3x3(cur_in, w_out) + b_out)  -> out[:, ti]
//   cur_out = relu(pred * w_proj + b_proj)          (bf16)
__global__ __launch_bounds__(256) void dec_fused(
    const unsigned short* __restrict__ cur_in, const float* __restrict__ w_out,
    const float* __restrict__ b_out, const float* __restrict__ w_proj,
    const float* __restrict__ b_proj, float* __restrict__ out,
    unsigned short* __restrict__ cur_out, int ti)
{
    int tid = threadIdx.x;
    int j  = tid & 7;
    int pp = tid >> 3;
    int b, y, x0;
    decode_dec(blockIdx.x, b, y, x0);
    int xx = x0 + pp;

    float s = 0.f;
    for (int dy = 0; dy < 3; ++dy) {
        int gy = y + dy - 1;
        if ((unsigned)gy >= HH) continue;
        #pragma unroll
        for (int dx = 0; dx < 3; ++dx) {
            int gx = xx + dx - 1;
            if ((unsigned)gx >= WW) continue;
            const uint4 cv = *(const uint4*)(cur_in + ((((size_t)b * HH + gy) * WW + gx) * FF + j * 8));
            const float4* wp = (const float4*)&w_out[(dy * 3 + dx) * FF + j * 8];
            float4 w0 = wp[0], w1 = wp[1];
            unsigned cx = cv.x, cy = cv.y, cz = cv.z, cw = cv.w;
            s += __uint_as_float(cx << 16) * w0.x + __uint_as_float(cx & 0xFFFF0000u) * w0.y
               + __uint_as_float(cy << 16) * w0.z + __uint_as_float(cy & 0xFFFF0000u) * w0.w
               + __uint_as_float(cz << 16) * w1.x + __uint_as_float(cz & 0xFFFF0000u) * w1.y
               + __uint_as_float(cw << 16) * w1.z + __uint_as_float(cw & 0xFFFF0000u) * w1.w;
        }
    }
    s += __shfl_xor(s, 1);
    s += __shfl_xor(s, 2);
    s += __shfl_xor(s, 4);
    float pv = sigf(s + b_out[0]);

    size_t pix = (((size_t)b * HH + y) * WW + xx);
    if (j == 0)
        out[((size_t)b * PRED_LEN + ti) * (HH * WW) + (size_t)y * WW + xx] = pv;

    const float4* wp = (const float4*)w_proj;
    const float4* bp = (const float4*)b_proj;
    float4 w0 = wp[j * 2], w1 = wp[j * 2 + 1];
    float4 b0 = bp[j * 2], b1 = bp[j * 2 + 1];
    short8 o;
    o[0] = (short)f2bf(fmaxf(fmaf(pv, w0.x, b0.x), 0.f));
    o[1] = (short)f2bf(fmaxf(fmaf(pv, w0.y, b0.y), 0.f));
    o[2] = (short)f2bf(fmaxf(fmaf(pv, w0.z, b0.z), 0.f));
    o[3] = (short)f2bf(fmaxf(fmaf(pv, w0.w, b0.w), 0.f));
    o[4] = (short)f2bf(fmaxf(fmaf(pv, w1.x, b1.x), 0.f));
    o[5] = (short)f2bf(fmaxf(fmaf(pv, w1.y, b1.y), 0.f));
    o[6] = (short)f2bf(fmaxf(fmaf(pv, w1.z, b1.z), 0.f));
    o[7] = (short)f2bf(fmaxf(fmaf(pv, w1.w, b1.w), 0.f));
    *(short8*)(cur_out + pix * FF + j * 8) = o;
}

extern "C" void kernel_launch(void* const* d_in, const int* in_sizes, int n_in,
                              void* d_out, int out_size, void* d_ws, size_t ws_size,
                              hipStream_t stream)
{
    const float* x      = (const float*)d_in[0];
    const float* wk     = (const float*)d_in[1];
    const float* wr     = (const float*)d_in[2];
    const float* bias   = (const float*)d_in[3];
    const float* w_out  = (const float*)d_in[4];
    const float* b_out  = (const float*)d_in[5];
    const float* w_proj = (const float*)d_in[6];
    const float* b_proj = (const float*)d_in[7];
    float* out = (float*)d_out;

    const size_t SB = (size_t)BB * HH * WW * FF;   // 8388608 elems
    unsigned short* h_a = (unsigned short*)d_ws;
    unsigned short* h_b = h_a + SB;
    float* cb = (float*)((char*)d_ws + 2 * SB * sizeof(unsigned short));
    short8* packed = (short8*)((char*)cb + SB * sizeof(float));  // 19456*16 B

    pack_wr<<<76, 256, 0, stream>>>(wr, wk, bias, packed);

    const int NBLK_STEP = (WW / TW) * HH * BB;    // 2048
    const int NBLK_DEC  = (WW / TWD) * HH * BB;   // 4096
    unsigned short* bufs[2] = {h_a, h_b};
    // FIRST writes every c/h element before any read -> no memset needed.
    lstm_step_mfma<true><<<NBLK_STEP, 256, 0, stream>>>(x, 0, bufs[0], cb, bufs[1], packed);
    for (int t = 1; t < TT; ++t) {
        lstm_step_mfma<false><<<NBLK_STEP, 256, 0, stream>>>(x, t, bufs[t & 1], cb,
                                                             bufs[(t + 1) & 1], packed);
    }

    for (int ti = 0; ti < PRED_LEN; ++ti) {
        dec_fused<<<NBLK_DEC, 256, 0, stream>>>(
            bufs[ti & 1], w_out, b_out, w_proj, b_proj, out, bufs[(ti + 1) & 1], ti);
    }
}

// Round 10
// 750.297 us; speedup vs baseline: 2.6711x; 1.0914x over previous
//
#include <hip/hip_runtime.h>
#include <math.h>

#define BB 8
#define TT 12
#define HH 128
#define WW 128
#define FF 64
#define GG 256   // 4*FF
#define PRED_LEN 6
#define TW 64     // pixels per block along W (step kernel)
#define TWD 32    // pixels per block along W (decoder)

typedef __attribute__((ext_vector_type(8))) short short8;
typedef __attribute__((ext_vector_type(4))) float floatx4;

__device__ __forceinline__ float sigf(float x) { return 1.f / (1.f + __expf(-x)); }
__device__ __forceinline__ float tanhfast(float x) { return 1.f - 2.f / (__expf(2.f * x) + 1.f); }

__device__ __forceinline__ unsigned short f2bf(float x) {
    unsigned u = __float_as_uint(x);
    u = (u + 0x7FFFu + ((u >> 16) & 1u)) >> 16;
    return (unsigned short)u;
}

// Step-grid XCD swizzle: 1024 blocks (2 x-tiles x 64 y-pairs x 8 b),
// 1024%8==0 -> bijective. One batch per XCD, y-contiguous (R8-proven:
// halo reads become same-XCD L2 hits, FETCH 58->40 MB).
__device__ __forceinline__ void decode_step(int wg, int& b, int& y, int& x0) {
    int lin = (wg & 7) * 128 + (wg >> 3);   // [0,1024)
    b = lin >> 7;                           // 128 blocks per batch
    int rem = lin & 127;
    y = (rem >> 1) * 2;                     // y-pair base row
    x0 = (rem & 1) * TW;
}

// Decoder swizzle (R6/R7-proven): 4096 blocks.
__device__ __forceinline__ void decode_dec(int wg, int& b, int& y, int& x0) {
    int lin = (wg & 7) * 512 + (wg >> 3);
    b = lin >> 9;
    int rem = lin & 511;
    y = rem >> 2;
    x0 = (rem & 3) * TWD;
}

// Pack B-fragments for mfma_f32_16x16x32_bf16.  (R5-proven, unchanged.)
// Chunks 0..17 (wr): c = tap*2+kc; lane = col + 16*kpart holds B[k][n],
//   k = kc*32 + kpart*8 + j, n = nt*16 + col.
// Chunk 18 (x-conv + bias): B[k][n] = k<9 ? wk[k][n] : k==9 ? bias[n] : 0.
__global__ __launch_bounds__(256) void pack_wr(
    const float* __restrict__ wr, const float* __restrict__ wk,
    const float* __restrict__ bias, short8* __restrict__ packed)
{
    int e = blockIdx.x * 256 + threadIdx.x;   // 19456 entries
    if (e >= 19 * 16 * 64) return;
    int lane = e & 63;
    int rest = e >> 6;
    int nt = rest & 15;
    int ch = rest >> 4;        // 0..18
    int col = lane & 15, kpart = lane >> 4;
    int n = nt * 16 + col;
    short8 v;
    if (ch < 18) {
        int kc = ch & 1, tap = ch >> 1;
        #pragma unroll
        for (int j = 0; j < 8; ++j) {
            int k = kc * 32 + kpart * 8 + j;
            v[j] = (short)f2bf(wr[((size_t)(tap * 64 + k)) * GG + n]);
        }
    } else {
        #pragma unroll
        for (int j = 0; j < 8; ++j) {
            int k = kpart * 8 + j;
            unsigned short r = 0;
            if (k < 9) r = f2bf(wk[k * GG + n]);
            else if (k == 9) r = f2bf(bias[n]);   // bias row (A has 1.0 there)
            v[j] = (short)r;
        }
    }
    packed[e] = v;
}

// Fused ConvLSTM step, double-row blocks (R9).
// Block = 512 threads = 8 waves: waves 0-3 compute row y (roles as R8's
// waves 0-3), waves 4-7 compute row y+1 with IDENTICAL packedB addresses
// -> the 311KB/block weight stream is read once per block instead of once
// per 64 pixels (halves the dominant L2 traffic). Per-wave registers are
// identical to R8 (acc 64 AGPR + ~64 VGPR = 128 unified -> 4 waves/SIMD).
template<bool FIRST>
__global__ __launch_bounds__(512, 4) void lstm_step_mfma(
    const float* __restrict__ x,             // (B,T,H,W,1) fp32
    int t,
    const unsigned short* __restrict__ h_in, // (B,H,W,F) bf16
    float* __restrict__ c_buf,               // (B,H,W,F) fp32 in/out
    unsigned short* __restrict__ h_out,      // (B,H,W,F) bf16
    const short8* __restrict__ packedB)      // packed wr | wk+bias
{
    __shared__ __align__(16) unsigned short sh[4 * 66 * FF];  // swizzled bf16 h, rows y-1..y+2
    __shared__ __align__(16) unsigned short sxa[2][TW * 32];  // swizzled x A-frags per row
    __shared__ float sx[4][66];

    const int tid = threadIdx.x;
    int b, y, x0;
    decode_step(blockIdx.x, b, y, x0);
    char* shb = (char*)sh;

    if (!FIRST) {
        // stage h tile: 4 rows x 66 cols x 64 ch bf16, 16B chunks, XOR-swizzled
        for (int i = tid; i < 4 * 66 * 8; i += 512) {
            int cq  = i & 7;
            int rc  = i >> 3;
            int col = rc % 66, r = rc / 66;
            int gy = y + r - 1, gx = x0 + col - 1;
            uint4 v = make_uint4(0u, 0u, 0u, 0u);
            if ((unsigned)gy < HH && (unsigned)gx < WW)
                v = *(const uint4*)(h_in + ((((size_t)b * HH + gy) * WW + gx) * FF + cq * 8));
            int byte = ((r * 66 + col) * FF + cq * 8) * 2;
            byte ^= ((col & 7) << 4);
            *(uint4*)(shb + byte) = v;
        }
    }
    // stage x tile (fp32), 4 rows
    for (int i = tid; i < 4 * 66; i += 512) {
        int col = i % 66, r = i / 66;
        int gy = y + r - 1, gx = x0 + col - 1;
        float v = 0.f;
        if ((unsigned)gy < HH && (unsigned)gx < WW)
            v = x[(((size_t)b * TT + t) * HH + gy) * WW + gx];
        sx[r][col] = v;
    }
    __syncthreads();

    // build x A-fragment tiles (one per row): sxa[rr][px][k], k<9 taps from
    // sx rows rr..rr+2, k==9 -> 1.0 (bias slot), else 0
    {
        int rr  = tid >> 8;        // row tile 0/1
        int t2  = tid & 255;
        int px  = t2 >> 2, kpc = t2 & 3;
        short8 v;
        #pragma unroll
        for (int j = 0; j < 8; ++j) {
            int k = kpc * 8 + j;
            unsigned short r = 0;
            if (k < 9) r = f2bf(sx[rr + k / 3][px + (k % 3)]);
            else if (k == 9) r = (unsigned short)0x3F80;   // 1.0 multiplies bias row
            v[j] = (short)r;
        }
        int byte = (px * 64 + kpc * 16) ^ ((px & 7) << 4);
        *(short8*)((char*)sxa[rr] + byte) = v;
    }
    __syncthreads();

    const int l    = tid & 63;
    const int w    = tid >> 6;     // 0..7
    const int sw   = w & 3;        // sub-wave role (R8's wave id)
    const int rrow = w >> 2;       // which row of the pair
    const int lc = l & 15;
    const int kp = l >> 4;
    const int gcol = sw * 16 + lc;   // feature index 0..63

    floatx4 acc[4][4];
    #pragma unroll
    for (int m = 0; m < 4; ++m)
        #pragma unroll
        for (int q = 0; q < 4; ++q)
            acc[m][q] = (floatx4){0.f, 0.f, 0.f, 0.f};

    if (!FIRST) {
        // recurrent conv: 18 chunks, single-buffered (R4/R5-proven)
        #pragma unroll
        for (int c = 0; c < 18; ++c) {
            const int tap_ = c >> 1, kc_ = c & 1, dy_ = tap_ / 3, dx_ = tap_ % 3;
            short8 af[4], bf[4];
            #pragma unroll
            for (int m_ = 0; m_ < 4; ++m_) {
                const int col_ = m_ * 16 + lc + dx_;
                int byte_ = (((dy_ + rrow) * 66 + col_) * FF + kc_ * 32 + kp * 8) * 2;
                byte_ ^= ((col_ & 7) << 4);
                af[m_] = *(const short8*)(shb + byte_);
            }
            #pragma unroll
            for (int q_ = 0; q_ < 4; ++q_)
                bf[q_] = packedB[(size_t)(c * 16 + (q_ * 4 + sw)) * 64 + l];
            #pragma unroll
            for (int m_ = 0; m_ < 4; ++m_)
                #pragma unroll
                for (int q_ = 0; q_ < 4; ++q_)
                    acc[m_][q_] = __builtin_amdgcn_mfma_f32_16x16x32_bf16(
                        af[m_], bf[q_], acc[m_][q_], 0, 0, 0);
        }
    }
    {
        // chunk 18: input conv + bias
        short8 af[4], bf[4];
        #pragma unroll
        for (int m_ = 0; m_ < 4; ++m_) {
            const int px_ = m_ * 16 + lc;
            int byte_ = (px_ * 64 + kp * 16) ^ ((px_ & 7) << 4);
            af[m_] = *(const short8*)((const char*)sxa[rrow] + byte_);
        }
        #pragma unroll
        for (int q_ = 0; q_ < 4; ++q_)
            bf[q_] = packedB[(size_t)(18 * 16 + (q_ * 4 + sw)) * 64 + l];
        #pragma unroll
        for (int m_ = 0; m_ < 4; ++m_)
            #pragma unroll
            for (int q_ = 0; q_ < 4; ++q_)
                acc[m_][q_] = __builtin_amdgcn_mfma_f32_16x16x32_bf16(
                    af[m_], bf[q_], acc[m_][q_], 0, 0, 0);
    }

    // epilogue: gates + cell update only (Keras order i,f,g,o)
    #pragma unroll
    for (int m = 0; m < 4; ++m) {
        #pragma unroll
        for (int r = 0; r < 4; ++r) {
            int p = m * 16 + kp * 4 + r;   // pixel within tile
            size_t idx = (((size_t)b * HH + (y + rrow)) * WW + (x0 + p)) * FF + gcol;
            float cp = FIRST ? 0.f : c_buf[idx];
            float iv = sigf(acc[m][0][r]);
            float fv = sigf(acc[m][1][r]);
            float gv = tanhfast(acc[m][2][r]);
            float ov = sigf(acc[m][3][r]);
            float cn = fv * cp + iv * gv;
            float hn = ov * tanhfast(cn);
            c_buf[idx] = cn;
            h_out[idx] = f2bf(hn);
        }
    }
}

// Fused decoder iteration (R6/R7-proven):
//   pred = sigmoid(conv3x3(cur_in, w_out) + b_out)  -> out[:, ti]
//   cur_out = relu(pred * w_proj + b_proj)          (bf16)
__global__ __launch_bounds__(256) void dec_fused(
    const unsigned short* __restrict__ cur_in, const float* __restrict__ w_out,
    const float* __restrict__ b_out, const float* __restrict__ w_proj,
    const float* __restrict__ b_proj, float* __restrict__ out,
    unsigned short* __restrict__ cur_out, int ti)
{
    int tid = threadIdx.x;
    int j  = tid & 7;
    int pp = tid >> 3;
    int b, y, x0;
    decode_dec(blockIdx.x, b, y, x0);
    int xx = x0 + pp;

    float s = 0.f;
    for (int dy = 0; dy < 3; ++dy) {
        int gy = y + dy - 1;
        if ((unsigned)gy >= HH) continue;
        #pragma unroll
        for (int dx = 0; dx < 3; ++dx) {
            int gx = xx + dx - 1;
            if ((unsigned)gx >= WW) continue;
            const uint4 cv = *(const uint4*)(cur_in + ((((size_t)b * HH + gy) * WW + gx) * FF + j * 8));
            const float4* wp = (const float4*)&w_out[(dy * 3 + dx) * FF + j * 8];
            float4 w0 = wp[0], w1 = wp[1];
            unsigned cx = cv.x, cy = cv.y, cz = cv.z, cw = cv.w;
            s += __uint_as_float(cx << 16) * w0.x + __uint_as_float(cx & 0xFFFF0000u) * w0.y
               + __uint_as_float(cy << 16) * w0.z + __uint_as_float(cy & 0xFFFF0000u) * w0.w
               + __uint_as_float(cz << 16) * w1.x + __uint_as_float(cz & 0xFFFF0000u) * w1.y
               + __uint_as_float(cw << 16) * w1.z + __uint_as_float(cw & 0xFFFF0000u) * w1.w;
        }
    }
    s += __shfl_xor(s, 1);
    s += __shfl_xor(s, 2);
    s += __shfl_xor(s, 4);
    float pv = sigf(s + b_out[0]);

    size_t pix = (((size_t)b * HH + y) * WW + xx);
    if (j == 0)
        out[((size_t)b * PRED_LEN + ti) * (HH * WW) + (size_t)y * WW + xx] = pv;

    const float4* wp = (const float4*)w_proj;
    const float4* bp = (const float4*)b_proj;
    float4 w0 = wp[j * 2], w1 = wp[j * 2 + 1];
    float4 b0 = bp[j * 2], b1 = bp[j * 2 + 1];
    short8 o;
    o[0] = (short)f2bf(fmaxf(fmaf(pv, w0.x, b0.x), 0.f));
    o[1] = (short)f2bf(fmaxf(fmaf(pv, w0.y, b0.y), 0.f));
    o[2] = (short)f2bf(fmaxf(fmaf(pv, w0.z, b0.z), 0.f));
    o[3] = (short)f2bf(fmaxf(fmaf(pv, w0.w, b0.w), 0.f));
    o[4] = (short)f2bf(fmaxf(fmaf(pv, w1.x, b1.x), 0.f));
    o[5] = (short)f2bf(fmaxf(fmaf(pv, w1.y, b1.y), 0.f));
    o[6] = (short)f2bf(fmaxf(fmaf(pv, w1.z, b1.z), 0.f));
    o[7] = (short)f2bf(fmaxf(fmaf(pv, w1.w, b1.w), 0.f));
    *(short8*)(cur_out + pix * FF + j * 8) = o;
}

extern "C" void kernel_launch(void* const* d_in, const int* in_sizes, int n_in,
                              void* d_out, int out_size, void* d_ws, size_t ws_size,
                              hipStream_t stream)
{
    const float* x      = (const float*)d_in[0];
    const float* wk     = (const float*)d_in[1];
    const float* wr     = (const float*)d_in[2];
    const float* bias   = (const float*)d_in[3];
    const float* w_out  = (const float*)d_in[4];
    const float* b_out  = (const float*)d_in[5];
    const float* w_proj = (const float*)d_in[6];
    const float* b_proj = (const float*)d_in[7];
    float* out = (float*)d_out;

    const size_t SB = (size_t)BB * HH * WW * FF;   // 8388608 elems
    unsigned short* h_a = (unsigned short*)d_ws;
    unsigned short* h_b = h_a + SB;
    float* cb = (float*)((char*)d_ws + 2 * SB * sizeof(unsigned short));
    short8* packed = (short8*)((char*)cb + SB * sizeof(float));  // 19456*16 B

    pack_wr<<<76, 256, 0, stream>>>(wr, wk, bias, packed);

    const int NBLK_STEP = (WW / TW) * (HH / 2) * BB;   // 1024 (double-row blocks)
    const int NBLK_DEC  = (WW / TWD) * HH * BB;        // 4096
    unsigned short* bufs[2] = {h_a, h_b};
    // FIRST writes every c/h element before any read -> no memset needed.
    lstm_step_mfma<true><<<NBLK_STEP, 512, 0, stream>>>(x, 0, bufs[0], cb, bufs[1], packed);
    for (int t = 1; t < TT; ++t) {
        lstm_step_mfma<false><<<NBLK_STEP, 512, 0, stream>>>(x, t, bufs[t & 1], cb,
                                                             bufs[(t + 1) & 1], packed);
    }

    for (int ti = 0; ti < PRED_LEN; ++ti) {
        dec_fused<<<NBLK_DEC, 256, 0, stream>>>(
            bufs[ti & 1], w_out, b_out, w_proj, b_proj, out, bufs[(ti + 1) & 1], ti);
    }
}